// Round 13
// baseline (447.195 us; speedup 1.0000x reference)
//
#include <hip/hip_runtime.h>
#include <hip/hip_bf16.h>

typedef unsigned short u16;
typedef __attribute__((ext_vector_type(8))) short bf16x8;    // 8 bf16 in 4 VGPRs
typedef __attribute__((ext_vector_type(16))) float f32x16;

static __device__ __forceinline__ u16 f2bf(float f) {
    unsigned u = __float_as_uint(f);
    unsigned r = (u + 0x7fffu + ((u >> 16) & 1u)) >> 16;   // RNE
    return (u16)r;
}
static __device__ __forceinline__ float bf2f(u16 u) {
    return __uint_as_float(((unsigned)u) << 16);
}

static __device__ __forceinline__ void async_copy16(const void* gptr, void* lptr) {
    __builtin_amdgcn_global_load_lds(
        (const __attribute__((address_space(1))) void*)gptr,
        (__attribute__((address_space(3))) void*)lptr, 16, 0, 0);
}

// ---------------------------------------------------------------------------
// fp32 -> bf16 for all three inputs, grid-stride (4096 blocks x 8 iters).
// ---------------------------------------------------------------------------
__global__ __launch_bounds__(256)
void cvt_all(const float* __restrict__ a, const float* __restrict__ b,
             const float* __restrict__ c,
             u16* __restrict__ oa, u16* __restrict__ ob, u16* __restrict__ oc) {
#pragma unroll
    for (int it = 0; it < 8; it++) {
        long li = ((long)it << 20) + (long)blockIdx.x * 256 + threadIdx.x;
        const float* src; u16* dst; long u;
        if (li < 4194304)      { src = a; dst = oa; u = li; }
        else if (li < 7340032) { src = b; dst = ob; u = li - 4194304; }
        else                   { src = c; dst = oc; u = li - 7340032; }
        long i = u * 4;
        float4 f = *(const float4*)(src + i);
        u16 o[4] = { f2bf(f.x), f2bf(f.y), f2bf(f.z), f2bf(f.w) };
        *(uint2*)(dst + i) = *(const uint2*)o;
    }
}

// ---------------------------------------------------------------------------
// C[m,n] = sum_k A[m,k] * B[n,k]   (row-major, K contiguous — "BT" gemm)
//
// R13 = R12 with MFMA shape 16x16x32 -> 32x32x16 (µbench pipe: 2382-2495 vs
// 2075 TF). R2/R3/R5's 1.9e7 conflicts were the 2-BIT XOR (kc^((r>>1)&3):
// 64 lanes fold onto 4 slot-groups = 4 lanes/bank); with the 3-BIT XOR
// kc^(r&7) (= R1/R6's staging formula, already implemented) chunk mf*2+hi1
// over rows l32 hits all 8 slots = 2 lanes/bank = free (m136). Staging code,
// stage/vmcnt calendar, read counts (12/4/8/0), LGKM counts all unchanged.
//
// 256x256 tile, BK=64, 512 threads = 8 waves (2M x 4N); wave tile 128x64 as
// 4 M-frags x (1 N-frag x 2 regions) of mfma_f32_32x32x16_bf16 (mappings
// refcheck-validated in R5). Per phase = quadrant (Mq,Nq) = 8 MFMA split
// 4+4 by m with counted mid-wait.
//
// FUSED mode (gemm1): panels bx<16 = Bx panels (region N0 <- Win B rows,
// N1 <- x rows; slot s <-> h = bx*128+s; read slot wn*32+l32 -> SAME h for
// both regions; epilogue writes f2bf(accB*accX)). Panels bx>=16 = C panels.
//
// LDS (2 dbufs x 32768 u16): A-Mq at Mq*8192, B-Nq at 16384+Nq*8192; 16B
// slot s = kc ^ (rowslot&7); swizzle pre-applied on the GLOBAL source.
// Stage calendar: ph1 A0' ph2 B0' ph3 A1' ph4 B1' -> other buf (2 copies
// each); vmcnt(4)@ph4 retires A0',B0'; vmcnt(2)@ph1 retires A1,B1; WAR >= 3
// barriers; queue never drained to 0 in-loop. Tail junk-stage re-stages the
// L2-hot current K-slice. M,N mult of 256, K mult of 128, grid.x mult of 8.
// ---------------------------------------------------------------------------
template<bool FUSED>
__global__ __launch_bounds__(512, 2)
void gemm_bt8(const u16* __restrict__ A, const u16* __restrict__ B,
              u16* __restrict__ oBx, u16* __restrict__ oC,
              float* __restrict__ oF, int M, int N, int K) {
    __shared__ __align__(16) u16 lds[65536];   // 128 KiB

    const int t    = threadIdx.x;              // 0..511
    const int lane = t & 63;
    const int wm   = (t >> 6) >> 2;            // 0..1
    const int wn   = (t >> 6) & 3;             // 0..3
    const int l32  = lane & 31;
    const int hi1  = lane >> 5;                // 0..1
    const int l7   = lane & 7;

    // XCD-aware panel remap (bijective since gridDim.x % 8 == 0)
    const int id   = blockIdx.y * gridDim.x + blockIdx.x;
    const int cpx  = gridDim.x >> 3;
    const int bx   = (id & 7) * cpx + ((id >> 3) % cpx);
    const int by   = (id >> 3) / cpx;
    const long rowA = (long)by * 256;

    // ---- staging sources (pre-swizzled global addresses, R12-verbatim) ----
    const int pl0 = t >> 3;                               // 0..63
    const int slotcol = ((t & 7) ^ (pl0 & 7)) * 8;
    const u16* Asrc[2][2]; const u16* Bsrc[2][2];
#pragma unroll
    for (int h = 0; h < 2; h++) {
        int gA0 = h * 64 + pl0;
        int gA1 = 128 + h * 64 + pl0;
        Asrc[h][0] = A + (rowA + gA0) * (long)K + slotcol;
        Asrc[h][1] = A + (rowA + gA1) * (long)K + slotcol;
    }
    if (FUSED && bx < 16) {
        const long rB = (long)bx * 128 + pl0;
        Bsrc[0][0] = B + rB * (long)K + slotcol;
        Bsrc[0][1] = Bsrc[0][0] + 64 * (long)K;
        Bsrc[1][0] = B + (4096 + rB) * (long)K + slotcol;
        Bsrc[1][1] = Bsrc[1][0] + 64 * (long)K;
    } else {
        const long rowB = FUSED ? (2048 + (long)(bx - 16) * 256)
                                : (long)bx * 256;
#pragma unroll
        for (int h = 0; h < 2; h++) {
            int nB0 = (pl0 >> 5) * 64 + h * 32 + (pl0 & 31);
            Bsrc[h][0] = B + (rowB + nB0) * (long)K + slotcol;
            Bsrc[h][1] = Bsrc[h][0] + 128 * (long)K;
        }
    }
    const int t8 = t * 8;

    auto STAGE_A = [&](int bufo, int h, int kk) {
        u16* d = lds + bufo + h * 8192 + t8;
        async_copy16(Asrc[h][0] + kk, d);
        async_copy16(Asrc[h][1] + kk, d + 4096);
    };
    auto STAGE_B = [&](int bufo, int h, int kk) {
        u16* d = lds + bufo + 16384 + h * 8192 + t8;
        async_copy16(Bsrc[h][0] + kk, d);
        async_copy16(Bsrc[h][1] + kk, d + 4096);
    };

    // ---- fragment read offsets (u16 units), 32x32 3-bit-XOR geometry ----
    // read addr = bufo + region + slot*64 + ((kc ^ (slot&7))*8), kc = mf*2+hi1
    // slot&7 == lane&7 for both A (slot = wm*64+m*32+l32) and B (wn*32+l32)
    const int aBase = (wm * 64 + l32) * 64;    // + Mq*8192 + m*2048
    const int bBase = 16384 + (wn * 32 + l32) * 64;   // + Nq*8192
    const int cof[4] = { ((0 * 2 + hi1) ^ l7) * 8, ((1 * 2 + hi1) ^ l7) * 8,
                         ((2 * 2 + hi1) ^ l7) * 8, ((3 * 2 + hi1) ^ l7) * 8 };

    bf16x8 af[2][4], ba[4], bb[4];
    f32x16 acc[4][2] = {};

    auto LOAD_A = [&](int bufo, int Mq, int m) {     // 4 b128 -> af[m]
        const u16* p = lds + bufo + Mq * 8192 + aBase + m * 2048;
#pragma unroll
        for (int mf = 0; mf < 4; mf++)
            af[m][mf] = *(const bf16x8*)(p + cof[mf]);
    };
    auto LOAD_B = [&](bf16x8 (&bg)[4], int bufo, int Nq) {  // 4 b128
        const u16* p = lds + bufo + Nq * 8192 + bBase;
#pragma unroll
        for (int mf = 0; mf < 4; mf++)
            bg[mf] = *(const bf16x8*)(p + cof[mf]);
    };

#define MF4(MQ, NQ, m, BG) do {                                              \
    __builtin_amdgcn_s_setprio(1);                                           \
    _Pragma("unroll")                                                        \
    for (int mf = 0; mf < 4; mf++)                                           \
        acc[(MQ) * 2 + (m)][NQ] = __builtin_amdgcn_mfma_f32_32x32x16_bf16(   \
            af[m][mf], BG[mf], acc[(MQ) * 2 + (m)][NQ], 0, 0, 0);            \
    __builtin_amdgcn_s_setprio(0);                                           \
} while (0)

#define BAR()   __builtin_amdgcn_s_barrier()
#define SB()    __builtin_amdgcn_sched_barrier(0)
#define LGKM(n) do { asm volatile("s_waitcnt lgkmcnt(" #n ")" ::: "memory"); \
                     __builtin_amdgcn_sched_barrier(0); } while (0)
#define VM(n)   asm volatile("s_waitcnt vmcnt(" #n ")" ::: "memory")

    // one K-tile = 4 phases, 1 barrier each; reads from BC, stages -> BN
#define TILE(BC, BN, KK)                                                     \
    /*ph1 Q(M0N0)*/                                                          \
    LOAD_B(ba, BC, 0); LOAD_A(BC, 0, 0); SB(); LOAD_A(BC, 0, 1);             \
    STAGE_A(BN, 0, KK); VM(2);                                               \
    LGKM(4); MF4(0, 0, 0, ba); LGKM(0); MF4(0, 0, 1, ba); BAR();             \
    /*ph2 Q(M0N1)*/                                                          \
    LOAD_B(bb, BC, 1);                                                       \
    STAGE_B(BN, 0, KK);                                                      \
    LGKM(0); MF4(0, 1, 0, bb); MF4(0, 1, 1, bb); BAR();                      \
    /*ph3 Q(M1N1)*/                                                          \
    LOAD_A(BC, 1, 0); SB(); LOAD_A(BC, 1, 1);                                \
    STAGE_A(BN, 1, KK);                                                      \
    LGKM(4); MF4(1, 1, 0, bb); LGKM(0); MF4(1, 1, 1, bb); BAR();             \
    /*ph4 Q(M1N0)*/                                                          \
    STAGE_B(BN, 1, KK); VM(4);                                               \
    MF4(1, 0, 0, ba); MF4(1, 0, 1, ba); BAR();

    // ---- prologue: stage ALL of tile0 -> buf0 ----
    STAGE_A(0, 0, 0);  STAGE_B(0, 0, 0);
    STAGE_A(0, 1, 0);  STAGE_B(0, 1, 0);
    asm volatile("s_waitcnt vmcnt(0)" ::: "memory");
    BAR();

    const int NT = K >> 6;                     // K/64 tiles, even
#pragma unroll 1
    for (int i = 0; i < NT; i += 2) {
        int k1 = (i + 1) << 6;                               // tile i+1 src
        int k2 = (i + 2 < NT) ? (i + 2) << 6 : k1;           // tail: junk but
        TILE(0, 32768, k1);                                  //  L2-HOT, never
        TILE(32768, 0, k2);                                  //  read
    }
    // drain in-flight LDS-targeted loads / reads before LDS dealloc
    asm volatile("s_waitcnt vmcnt(0) lgkmcnt(0)" ::: "memory");

#undef TILE
#undef VM
#undef LGKM
#undef SB
#undef MF4
#undef BAR

    // ---- epilogue: 32x32 C/D layout col=l32, row=(r&3)+8*(r>>2)+4*hi1 ----
    // global row = rowA + wm*128 + Mq*64 + m*32 + rowt  (acc[Mq*2+m][Nq])
    if (FUSED && bx < 16) {
        // Bx panel: acc[i][0] = B, acc[i][1] = x at the SAME h
        const long hCol = (long)bx * 128 + wn * 32 + l32;
#pragma unroll
        for (int i = 0; i < 4; i++) {
            long rB = rowA + wm * 128 + (i >> 1) * 64 + (i & 1) * 32;
#pragma unroll
            for (int r = 0; r < 16; r++) {
                long row = rB + (r & 3) + 8 * (r >> 2) + 4 * hi1;
                float v = acc[i][0][r] * acc[i][1][r];
                oBx[row * 2048 + hCol] = f2bf(v);
            }
        }
    } else if (FUSED) {
        const long colB = (long)(bx - 16) * 256 + wn * 64 + l32;
#pragma unroll
        for (int i = 0; i < 4; i++) {
            long rB = rowA + wm * 128 + (i >> 1) * 64 + (i & 1) * 32;
#pragma unroll
            for (int nq = 0; nq < 2; nq++)
#pragma unroll
                for (int r = 0; r < 16; r++) {
                    long row = rB + (r & 3) + 8 * (r >> 2) + 4 * hi1;
                    oC[row * 2048 + colB + nq * 32] = f2bf(acc[i][nq][r]);
                }
        }
    } else {
        const long colB = (long)bx * 256 + wn * 64 + l32;
#pragma unroll
        for (int i = 0; i < 4; i++) {
            long rB = rowA + wm * 128 + (i >> 1) * 64 + (i & 1) * 32;
#pragma unroll
            for (int nq = 0; nq < 2; nq++)
#pragma unroll
                for (int r = 0; r < 16; r++) {
                    long row = rB + (r & 3) + 8 * (r >> 2) + 4 * hi1;
                    oF[row * (long)N + colB + nq * 32] = acc[i][nq][r];
                }
        }
    }
}

// ---------------------------------------------------------------------------
// Depthwise causal conv(L=3) + C-gate on precomputed Bx, 8 rows/block.
// Bx,Cc: (8192, 2048) bf16.  y[s,h] = C[s,h] * (w0*Bx[s-2,h] + w1*Bx[s-1,h]
// + w2*Bx[s,h]).  Batch boundary: s resets every 4096 rows; 4096%8==0.
// ---------------------------------------------------------------------------
union U16x8 { uint4 v; u16 u[8]; };

__global__ __launch_bounds__(256)
void conv_fuse(const u16* __restrict__ Bx, const u16* __restrict__ Cc,
               const float* __restrict__ cw, u16* __restrict__ y) {
    const int r0 = blockIdx.x * 8;         // 1024 blocks
    const int h0 = threadIdx.x * 8;        // 256*8 = 2048
    const int batch = r0 >> 12;

    U16x8 P[10];
#pragma unroll
    for (int ii = 0; ii < 10; ii++) {
        int g = r0 - 2 + ii;
        if (g >= 0 && (g >> 12) == batch)
            P[ii].v = *(const uint4*)(Bx + (long)g * 2048 + h0);
        else
            P[ii].v = make_uint4(0, 0, 0, 0);
    }
    float bx[10][8];
#pragma unroll
    for (int ii = 0; ii < 10; ii++)
#pragma unroll
        for (int i = 0; i < 8; i++)
            bx[ii][i] = bf2f(P[ii].u[i]);

    float w0[8], w1[8], w2[8];
#pragma unroll
    for (int i = 0; i < 8; i++) {
        int h = h0 + i;
        w0[i] = cw[h * 3];     // tap s-2
        w1[i] = cw[h * 3 + 1]; // tap s-1
        w2[i] = cw[h * 3 + 2]; // tap s
    }

#pragma unroll
    for (int jj = 0; jj < 8; jj++) {
        U16x8 Cv, o;
        Cv.v = *(const uint4*)(Cc + (long)(r0 + jj) * 2048 + h0);
#pragma unroll
        for (int i = 0; i < 8; i++) {
            float v = w2[i] * bx[jj + 2][i] + w1[i] * bx[jj + 1][i]
                    + w0[i] * bx[jj][i];
            o.u[i] = f2bf(v * bf2f(Cv.u[i]));
        }
        *(uint4*)(y + (long)(r0 + jj) * 2048 + h0) = o.v;
    }
}

// ---------------------------------------------------------------------------
extern "C" void kernel_launch(void* const* d_in, const int* in_sizes, int n_in,
                              void* d_out, int out_size, void* d_ws, size_t ws_size,
                              hipStream_t stream) {
    const float* hs   = (const float*)d_in[0];   // (2,4096,2048)
    const float* Win  = (const float*)d_in[1];   // (6144,2048)
    const float* cw   = (const float*)d_in[2];   // (2048,1,3)
    const float* Wout = (const float*)d_in[3];   // (2048,2048)
    float* out = (float*)d_out;                  // (2,4096,2048) fp32

    char* ws = (char*)d_ws;
    u16* hsb   = (u16*)(ws);                     //  33,554,432 B
    u16* Winb  = (u16*)(ws +  33554432);         //  25,165,824 B
    u16* Woutb = (u16*)(ws +  58720256);         //   8,388,608 B
    u16* bxb   = (u16*)(ws +  67108864);         //  33,554,432 B
    u16* cb    = (u16*)(ws + 100663296);         //  33,554,432 B
    u16* yb    = (u16*)(ws + 134217728);         //  33,554,432 B  (end 167,772,160)

    cvt_all<<<4096, 256, 0, stream>>>(hs, Win, Wout, hsb, Winb, Woutb);

    // fused gemm1: Bx = (hs@WinB^T)*(hs@WinX^T), C = hs@WinC^T
    gemm_bt8<true ><<<dim3(24, 32), 512, 0, stream>>>(
        hsb, Winb, bxb, cb, nullptr, 8192, 2048, 2048);

    conv_fuse<<<1024, 256, 0, stream>>>(bxb, cb, cw, yb);

    // out = y @ Wout^T : M=8192, N=2048, K=2048  (grid 8x32 = 256 blocks)
    gemm_bt8<false><<<dim3(8, 32), 512, 0, stream>>>(
        yb, Woutb, nullptr, nullptr, out, 8192, 2048, 2048);
}